// Round 10
// baseline (358.055 us; speedup 1.0000x reference)
//
#include <hip/hip_runtime.h>

#define MODES 10
#define NPH 5
#define DEPTH 10
#define NST5 2002
#define BATCH 4096

// Module-scope scratch: allocated at .so load time, no hipMalloc, no ws_size
// dependence, cannot overrun into harness buffers. Fully rewritten every call
// before being read (deterministic, no cross-call state dependence).
__device__ unsigned short g_tbl[30020];
__device__ float g_probs[(size_t)BATCH * NST5];

// ---------- combinatorics: enumeration order of _enum(m,n) ----------
// count(m, n) = C(n+m-1, m-1)
__device__ __forceinline__ int d_count(int m, int n) {
    int k = m - 1, nn = n + m - 1;
    long r = 1;
    for (int i = 1; i <= k; i++) r = r * (nn - i + 1) / i;
    return (int)r;
}

__device__ void d_unrank(int r, int n, int* s) {
    for (int p = 0; p < MODES; p++) {
        int mm = MODES - p;
        if (mm == 1) { s[p] = n; return; }
        int k = n;
        for (; k >= 0; k--) {
            int c = d_count(mm - 1, n - k);
            if (r < c) break;
            r -= c;
        }
        s[p] = k; n -= k;
    }
}

__device__ int d_rank(const int* s, int n) {
    int r = 0;
    for (int p = 0; p < MODES && n > 0; p++) {
        int mm = MODES - p;
        if (mm == 1) break;
        for (int k = n; k > s[p]; k--) r += d_count(mm - 1, n - k);
        n -= s[p];
    }
    return r;
}

// Packed transition tables: per level k (transition k -> k+1 photons),
// layout [j][t] (transposed for coalescing): entry = parent_idx | (occ << 12)
__global__ void k_tables() {
    int id = blockIdx.x * 256 + threadIdx.x;
    if (id >= 3002) return;
    const int sizes[5] = {10, 55, 220, 715, 2002};
    const int offs[5]  = {0, 100, 650, 2850, 10000};
    int k = 0, t = id;
    while (k < 5 && t >= sizes[k]) { t -= sizes[k]; k++; }
    int s[10];
    d_unrank(t, k + 1, s);
    int N = sizes[k];
    for (int j = 0; j < MODES; j++) {
        unsigned short e = 0;
        if (s[j] > 0) {
            s[j]--;
            int p = d_rank(s, k);
            s[j]++;
            e = (unsigned short)(p | (s[j] << 12));
        }
        g_tbl[offs[k] + j * N + t] = e;
    }
}

// ---------- fused unitary build + SLOS per batch element ----------
__global__ __launch_bounds__(256)
void k_slos(const float* __restrict__ x, const float* __restrict__ theta) {
    __shared__ float2 Ush[MODES][NPH];   // columns 0..4 of U
    __shared__ float2 ampA[715];         // levels 0,2,4
    __shared__ float2 ampB[NST5];        // levels 1,3,5
    __shared__ float lut[8];

    const int b = blockIdx.x;
    const int tid = threadIdx.x;

    if (tid < 8) {
        const float lv[8] = {0.f, 1.f, 1.41421356237f, 1.73205080757f,
                             2.f, 2.2360679775f, 0.f, 0.f};
        lut[tid] = lv[tid];
    }

    // --- build U columns 0..4: thread (r,c) for tid < 50 ---
    const int r = tid / 5, c = tid % 5;
    const bool act = (tid < 50);
    float2 val = make_float2(0.f, 0.f);
    if (act && r == c) {
        float ang = 6.28318530717958647692f * x[b * MODES + r];
        float s_, c_; sincosf(ang, &s_, &c_);
        val = make_float2(c_, s_);
    }
    for (int l = 0; l < DEPTH; l++) {
        if (act && l > 0) {
            float ang = theta[(l - 1) * MODES + r];
            float s_, c_; sincosf(ang, &s_, &c_);
            float nx = val.x * c_ - val.y * s_;
            float ny = val.x * s_ + val.y * c_;
            val = make_float2(nx, ny);
        }
        if (act) Ush[r][c] = val;
        __syncthreads();
        float2 nv = val;
        if (act) {
            int o = l & 1;
            int lo = r - o;
            int partner = o + (lo ^ 1);
            if (lo >= 0 && partner < MODES) {
                float2 pb = Ush[partner][c];
                const float inv = 0.70710678118654752f;
                // new = inv * (own + i*partner)
                nv.x = inv * (val.x - pb.y);
                nv.y = inv * (val.y + pb.x);
            }
        }
        __syncthreads();
        val = nv;
    }
    if (act) Ush[r][c] = val;
    if (tid == 0) ampA[0] = make_float2(1.f, 0.f);
    __syncthreads();

    // --- SLOS: add photons one at a time ---
    const int Ns[5]   = {10, 55, 220, 715, 2002};
    const int offs[5] = {0, 100, 650, 2850, 10000};
    for (int k = 0; k < NPH; k++) {
        float2* src = (k & 1) ? ampB : ampA;
        float2* dst = (k & 1) ? ampA : ampB;
        float2 u[10];
        #pragma unroll
        for (int j = 0; j < MODES; j++) u[j] = Ush[j][k];
        const int N = Ns[k];
        const unsigned short* tk = g_tbl + offs[k];
        for (int t = tid; t < N; t += 256) {
            float ax = 0.f, ay = 0.f;
            #pragma unroll
            for (int j = 0; j < MODES; j++) {
                unsigned short e = tk[j * N + t];
                int idx = e & 0xFFF;
                float sq = lut[e >> 12];
                float2 a = src[idx];
                float tx = u[j].x * a.x - u[j].y * a.y;
                float ty = u[j].x * a.y + u[j].y * a.x;
                ax = fmaf(sq, tx, ax);
                ay = fmaf(sq, ty, ay);
            }
            dst[t] = make_float2(ax, ay);
        }
        __syncthreads();
    }

    // --- probs = |amp5|^2 -> global ---
    float* po = g_probs + (size_t)b * NST5;
    for (int t = tid; t < NST5; t += 256) {
        float2 a = ampB[t];
        po[t] = a.x * a.x + a.y * a.y;
    }
}

// ---------- out = probs @ W + b : 8 rows/block, K split over 4 waves ----------
__global__ __launch_bounds__(256)
void k_gemm(const float* __restrict__ W,
            const float* __restrict__ bias, float* __restrict__ out) {
    const int r0 = blockIdx.x * 8;
    const int wave = threadIdx.x >> 6;
    const int lane = threadIdx.x & 63;
    const int CH = 501;
    int k0 = wave * CH;
    int k1 = k0 + CH; if (k1 > NST5) k1 = NST5;

    float acc[8];
    #pragma unroll
    for (int i = 0; i < 8; i++) acc[i] = 0.f;

    for (int k = k0; k < k1; k++) {
        float wv = W[(size_t)k * 64 + lane];
        #pragma unroll
        for (int rr = 0; rr < 8; rr++)
            acc[rr] = fmaf(g_probs[(size_t)(r0 + rr) * NST5 + k], wv, acc[rr]);
    }

    __shared__ float part[4][8][64];
    #pragma unroll
    for (int rr = 0; rr < 8; rr++) part[wave][rr][lane] = acc[rr];
    __syncthreads();

    for (int o = threadIdx.x; o < 512; o += 256) {
        int rr = o >> 6, cc = o & 63;
        float v = part[0][rr][cc] + part[1][rr][cc] +
                  part[2][rr][cc] + part[3][rr][cc] + bias[cc];
        out[(size_t)(r0 + rr) * 64 + cc] = v;
    }
}

extern "C" void kernel_launch(void* const* d_in, const int* in_sizes, int n_in,
                              void* d_out, int out_size, void* d_ws, size_t ws_size,
                              hipStream_t stream) {
    const float* x     = (const float*)d_in[0];
    const float* theta = (const float*)d_in[1];
    const float* W     = (const float*)d_in[2];
    const float* bias  = (const float*)d_in[3];
    float* out = (float*)d_out;
    (void)d_ws; (void)ws_size; (void)in_sizes; (void)n_in; (void)out_size;

    k_tables<<<12, 256, 0, stream>>>();
    k_slos<<<4096, 256, 0, stream>>>(x, theta);
    k_gemm<<<512, 256, 0, stream>>>(W, bias, out);
}

// Round 12
// 234.571 us; speedup vs baseline: 1.5264x; 1.5264x over previous
//
#include <hip/hip_runtime.h>

#define MODES 10
#define NPH 5
#define DEPTH 10
#define NST5 2002
#define BATCH 4096

// Module-scope scratch: allocated at .so load, fully rewritten every call.
__device__ unsigned short g_tbl[30020];
__device__ float g_probs[(size_t)BATCH * NST5];
__device__ float g_part[4 * (size_t)BATCH * 64];

// ---------- combinatorics ----------
__device__ __forceinline__ int d_count(int m, int n) {
    int k = m - 1, nn = n + m - 1;
    long r = 1;
    for (int i = 1; i <= k; i++) r = r * (nn - i + 1) / i;
    return (int)r;
}

__device__ void d_unrank(int r, int n, int* s) {
    for (int p = 0; p < MODES; p++) {
        int mm = MODES - p;
        if (mm == 1) { s[p] = n; return; }
        int k = n;
        for (; k >= 0; k--) {
            int c = d_count(mm - 1, n - k);
            if (r < c) break;
            r -= c;
        }
        s[p] = k; n -= k;
    }
}

__device__ int d_rank(const int* s, int n) {
    int r = 0;
    for (int p = 0; p < MODES && n > 0; p++) {
        int mm = MODES - p;
        if (mm == 1) break;
        for (int k = n; k > s[p]; k--) r += d_count(mm - 1, n - k);
        n -= s[p];
    }
    return r;
}

// tables: per level k, layout [j][t]: entry = parent_idx | (occ << 12)
__global__ void k_tables() {
    int id = blockIdx.x * 256 + threadIdx.x;
    if (id >= 3002) return;
    const int sizes[5] = {10, 55, 220, 715, 2002};
    const int offs[5]  = {0, 100, 650, 2850, 10000};
    int k = 0, t = id;
    while (k < 5 && t >= sizes[k]) { t -= sizes[k]; k++; }
    int s[10];
    d_unrank(t, k + 1, s);
    int N = sizes[k];
    for (int j = 0; j < MODES; j++) {
        unsigned short e = 0;
        if (s[j] > 0) {
            s[j]--;
            int p = d_rank(s, k);
            s[j]++;
            e = (unsigned short)(p | (s[j] << 12));
        }
        g_tbl[offs[k] + j * N + t] = e;
    }
}

// ---------- fused unitary build + SLOS per batch element ----------
__global__ __launch_bounds__(256)
void k_slos(const float* __restrict__ x, const float* __restrict__ theta) {
    __shared__ float2 Ush[MODES][NPH];
    __shared__ float2 ampA[715];
    __shared__ float2 ampB[NST5];
    __shared__ float lut[8];

    const int b = blockIdx.x;
    const int tid = threadIdx.x;

    if (tid < 8) {
        const float lv[8] = {0.f, 1.f, 1.41421356237f, 1.73205080757f,
                             2.f, 2.2360679775f, 0.f, 0.f};
        lut[tid] = lv[tid];
    }

    const int r = tid / 5, c = tid % 5;
    const bool act = (tid < 50);
    float2 val = make_float2(0.f, 0.f);
    if (act && r == c) {
        float ang = 6.28318530717958647692f * x[b * MODES + r];
        float s_, c_; sincosf(ang, &s_, &c_);
        val = make_float2(c_, s_);
    }
    for (int l = 0; l < DEPTH; l++) {
        if (act && l > 0) {
            float ang = theta[(l - 1) * MODES + r];
            float s_, c_; sincosf(ang, &s_, &c_);
            float nx = val.x * c_ - val.y * s_;
            float ny = val.x * s_ + val.y * c_;
            val = make_float2(nx, ny);
        }
        if (act) Ush[r][c] = val;
        __syncthreads();
        float2 nv = val;
        if (act) {
            int o = l & 1;
            int lo = r - o;
            int partner = o + (lo ^ 1);
            if (lo >= 0 && partner < MODES) {
                float2 pb = Ush[partner][c];
                const float inv = 0.70710678118654752f;
                nv.x = inv * (val.x - pb.y);
                nv.y = inv * (val.y + pb.x);
            }
        }
        __syncthreads();
        val = nv;
    }
    if (act) Ush[r][c] = val;
    if (tid == 0) ampA[0] = make_float2(1.f, 0.f);
    __syncthreads();

    const int Ns[5]   = {10, 55, 220, 715, 2002};
    const int offs[5] = {0, 100, 650, 2850, 10000};
    for (int k = 0; k < NPH; k++) {
        float2* src = (k & 1) ? ampB : ampA;
        float2* dst = (k & 1) ? ampA : ampB;
        float2 u[10];
        #pragma unroll
        for (int j = 0; j < MODES; j++) u[j] = Ush[j][k];
        const int N = Ns[k];
        const unsigned short* tk = g_tbl + offs[k];
        for (int t = tid; t < N; t += 256) {
            float ax = 0.f, ay = 0.f;
            #pragma unroll
            for (int j = 0; j < MODES; j++) {
                unsigned short e = tk[j * N + t];
                int idx = e & 0xFFF;
                float sq = lut[e >> 12];
                float2 a = src[idx];
                float tx = u[j].x * a.x - u[j].y * a.y;
                float ty = u[j].x * a.y + u[j].y * a.x;
                ax = fmaf(sq, tx, ax);
                ay = fmaf(sq, ty, ay);
            }
            dst[t] = make_float2(ax, ay);
        }
        __syncthreads();
    }

    float* po = g_probs + (size_t)b * NST5;
    for (int t = tid; t < NST5; t += 256) {
        float2 a = ampB[t];
        po[t] = a.x * a.x + a.y * a.y;
    }
}

// ---------- GEMM: g_part[kc] = P[64-row tile] x W  (LDS-tiled, K split x4) ----------
// grid (64, 4), 256 threads. Thread (rg,cg) owns rows rg*4..+3, cols cg*4..+3.
__global__ __launch_bounds__(256)
void k_gemm2(const float* __restrict__ W) {
    __shared__ float P_lds[64][68];   // [row][kk], pad 68 for write-bank spread
    __shared__ float W_lds[64][68];   // [kk][col]

    const int bm = blockIdx.x;        // row tile
    const int kc = blockIdx.y;        // k chunk
    const int r0 = bm * 64;
    const int ks = kc * 501;
    const int ke = (ks + 501 < NST5) ? ks + 501 : NST5;

    const int tid = threadIdx.x;
    const int rg = tid >> 4;          // 0..15
    const int cg = tid & 15;          // 0..15
    const int srow = tid >> 4;        // staging row-in-pass
    const int sc4 = (tid & 15) * 4;   // staging col

    float acc[4][4];
    #pragma unroll
    for (int i = 0; i < 4; i++)
        #pragma unroll
        for (int j = 0; j < 4; j++) acc[i][j] = 0.f;

    for (int k0 = ks; k0 < ke; k0 += 64) {
        const int kw = ke - k0;       // <=64 valid ks this step
        __syncthreads();
        // stage P: 4 passes of 16 rows; row-major [row][kk]
        #pragma unroll
        for (int p = 0; p < 4; p++) {
            int row = p * 16 + srow;
            float4 v = make_float4(0.f, 0.f, 0.f, 0.f);
            if (sc4 < kw) {
                const float* src = &g_probs[(size_t)(r0 + row) * NST5 + k0 + sc4];
                if (sc4 + 4 <= kw) {
                    v = *(const float4*)src;
                } else {
                    float tmp[4] = {0.f, 0.f, 0.f, 0.f};
                    for (int i = 0; i < kw - sc4; i++) tmp[i] = src[i];
                    v = *(const float4*)tmp;
                }
            }
            *(float4*)&P_lds[row][sc4] = v;
        }
        // stage W: 4 passes of 16 k-rows; [kk][col]
        #pragma unroll
        for (int p = 0; p < 4; p++) {
            int krow = p * 16 + srow;
            float4 v = make_float4(0.f, 0.f, 0.f, 0.f);
            if (krow < kw)
                v = *(const float4*)&W[(size_t)(k0 + krow) * 64 + sc4];
            *(float4*)&W_lds[krow][sc4] = v;
        }
        __syncthreads();

        #pragma unroll 4
        for (int kk = 0; kk < 64; kk++) {
            float4 wv = *(const float4*)&W_lds[kk][cg * 4];
            float pr[4];
            #pragma unroll
            for (int i = 0; i < 4; i++) pr[i] = P_lds[rg * 4 + i][kk];
            #pragma unroll
            for (int i = 0; i < 4; i++) {
                acc[i][0] = fmaf(pr[i], wv.x, acc[i][0]);
                acc[i][1] = fmaf(pr[i], wv.y, acc[i][1]);
                acc[i][2] = fmaf(pr[i], wv.z, acc[i][2]);
                acc[i][3] = fmaf(pr[i], wv.w, acc[i][3]);
            }
        }
    }

    float* po = g_part + ((size_t)kc * BATCH + r0) * 64;
    #pragma unroll
    for (int i = 0; i < 4; i++) {
        float4 v = make_float4(acc[i][0], acc[i][1], acc[i][2], acc[i][3]);
        *(float4*)&po[(size_t)(rg * 4 + i) * 64 + cg * 4] = v;
    }
}

// ---------- reduce 4 partials + bias ----------
__global__ __launch_bounds__(256)
void k_reduce(const float* __restrict__ bias, float* __restrict__ out) {
    int i = blockIdx.x * 256 + threadIdx.x;
    const int TOT = BATCH * 64;
    if (i < TOT) {
        float v = g_part[i] + g_part[TOT + i] + g_part[2 * TOT + i]
                + g_part[3 * TOT + i] + bias[i & 63];
        out[i] = v;
    }
}

extern "C" void kernel_launch(void* const* d_in, const int* in_sizes, int n_in,
                              void* d_out, int out_size, void* d_ws, size_t ws_size,
                              hipStream_t stream) {
    const float* x     = (const float*)d_in[0];
    const float* theta = (const float*)d_in[1];
    const float* W     = (const float*)d_in[2];
    const float* bias  = (const float*)d_in[3];
    float* out = (float*)d_out;
    (void)d_ws; (void)ws_size; (void)in_sizes; (void)n_in; (void)out_size;

    k_tables<<<12, 256, 0, stream>>>();
    k_slos<<<4096, 256, 0, stream>>>(x, theta);
    k_gemm2<<<dim3(64, 4), 256, 0, stream>>>(W);
    k_reduce<<<1024, 256, 0, stream>>>(bias, out);
}

// Round 13
// 130.577 us; speedup vs baseline: 2.7421x; 1.7964x over previous
//
#include <hip/hip_runtime.h>

#define MODES 10
#define NPH 5
#define DEPTH 10
#define NST5 2002
#define BATCH 4096

// Module-scope scratch: allocated at .so load, fully rewritten every call.
__device__ unsigned short g_tbl[30020];
__device__ float g_probs[(size_t)BATCH * NST5];
__device__ float g_part[4 * (size_t)BATCH * 64];

// ---------- combinatorics ----------
// count(m, n) = C(n+m-1, m-1), m in [1,10], n in [0,5] -> exact constant LUT.
// (Old version computed this with a 9-iter i64 mul/div loop; i64 divide is a
//  ~100-cycle soft routine on gfx950 and made k_tables take 134 us.)
__device__ __forceinline__ int d_count(int m, int n) {
    static const unsigned short C[11][6] = {
        {0, 0, 0, 0, 0, 0},            // m=0 (unused)
        {1, 1, 1, 1, 1, 1},            // m=1
        {1, 2, 3, 4, 5, 6},            // m=2
        {1, 3, 6, 10, 15, 21},         // m=3
        {1, 4, 10, 20, 35, 56},        // m=4
        {1, 5, 15, 35, 70, 126},       // m=5
        {1, 6, 21, 56, 126, 252},      // m=6
        {1, 7, 28, 84, 210, 462},      // m=7
        {1, 8, 36, 120, 330, 792},     // m=8
        {1, 9, 45, 165, 495, 1287},    // m=9
        {1, 10, 55, 220, 715, 2002},   // m=10
    };
    return C[m][n];
}

__device__ void d_unrank(int r, int n, int* s) {
    for (int p = 0; p < MODES; p++) {
        int mm = MODES - p;
        if (mm == 1) { s[p] = n; return; }
        int k = n;
        for (; k >= 0; k--) {
            int c = d_count(mm - 1, n - k);
            if (r < c) break;
            r -= c;
        }
        s[p] = k; n -= k;
    }
}

__device__ int d_rank(const int* s, int n) {
    int r = 0;
    for (int p = 0; p < MODES && n > 0; p++) {
        int mm = MODES - p;
        if (mm == 1) break;
        for (int k = n; k > s[p]; k--) r += d_count(mm - 1, n - k);
        n -= s[p];
    }
    return r;
}

// tables: per level k, layout [j][t]: entry = parent_idx | (occ << 12)
__global__ void k_tables() {
    int id = blockIdx.x * 256 + threadIdx.x;
    if (id >= 3002) return;
    const int sizes[5] = {10, 55, 220, 715, 2002};
    const int offs[5]  = {0, 100, 650, 2850, 10000};
    int k = 0, t = id;
    while (k < 5 && t >= sizes[k]) { t -= sizes[k]; k++; }
    int s[10];
    d_unrank(t, k + 1, s);
    int N = sizes[k];
    for (int j = 0; j < MODES; j++) {
        unsigned short e = 0;
        if (s[j] > 0) {
            s[j]--;
            int p = d_rank(s, k);
            s[j]++;
            e = (unsigned short)(p | (s[j] << 12));
        }
        g_tbl[offs[k] + j * N + t] = e;
    }
}

// ---------- fused unitary build + SLOS per batch element ----------
__global__ __launch_bounds__(256)
void k_slos(const float* __restrict__ x, const float* __restrict__ theta) {
    __shared__ float2 Ush[MODES][NPH];
    __shared__ float2 ampA[715];
    __shared__ float2 ampB[NST5];
    __shared__ float lut[8];

    const int b = blockIdx.x;
    const int tid = threadIdx.x;

    if (tid < 8) {
        const float lv[8] = {0.f, 1.f, 1.41421356237f, 1.73205080757f,
                             2.f, 2.2360679775f, 0.f, 0.f};
        lut[tid] = lv[tid];
    }

    const int r = tid / 5, c = tid % 5;
    const bool act = (tid < 50);
    float2 val = make_float2(0.f, 0.f);
    if (act && r == c) {
        float ang = 6.28318530717958647692f * x[b * MODES + r];
        float s_, c_; sincosf(ang, &s_, &c_);
        val = make_float2(c_, s_);
    }
    for (int l = 0; l < DEPTH; l++) {
        if (act && l > 0) {
            float ang = theta[(l - 1) * MODES + r];
            float s_, c_; sincosf(ang, &s_, &c_);
            float nx = val.x * c_ - val.y * s_;
            float ny = val.x * s_ + val.y * c_;
            val = make_float2(nx, ny);
        }
        if (act) Ush[r][c] = val;
        __syncthreads();
        float2 nv = val;
        if (act) {
            int o = l & 1;
            int lo = r - o;
            int partner = o + (lo ^ 1);
            if (lo >= 0 && partner < MODES) {
                float2 pb = Ush[partner][c];
                const float inv = 0.70710678118654752f;
                nv.x = inv * (val.x - pb.y);
                nv.y = inv * (val.y + pb.x);
            }
        }
        __syncthreads();
        val = nv;
    }
    if (act) Ush[r][c] = val;
    if (tid == 0) ampA[0] = make_float2(1.f, 0.f);
    __syncthreads();

    const int Ns[5]   = {10, 55, 220, 715, 2002};
    const int offs[5] = {0, 100, 650, 2850, 10000};
    for (int k = 0; k < NPH; k++) {
        float2* src = (k & 1) ? ampB : ampA;
        float2* dst = (k & 1) ? ampA : ampB;
        float2 u[10];
        #pragma unroll
        for (int j = 0; j < MODES; j++) u[j] = Ush[j][k];
        const int N = Ns[k];
        const unsigned short* tk = g_tbl + offs[k];
        for (int t = tid; t < N; t += 256) {
            float ax = 0.f, ay = 0.f;
            #pragma unroll
            for (int j = 0; j < MODES; j++) {
                unsigned short e = tk[j * N + t];
                int idx = e & 0xFFF;
                float sq = lut[e >> 12];
                float2 a = src[idx];
                float tx = u[j].x * a.x - u[j].y * a.y;
                float ty = u[j].x * a.y + u[j].y * a.x;
                ax = fmaf(sq, tx, ax);
                ay = fmaf(sq, ty, ay);
            }
            dst[t] = make_float2(ax, ay);
        }
        __syncthreads();
    }

    float* po = g_probs + (size_t)b * NST5;
    for (int t = tid; t < NST5; t += 256) {
        float2 a = ampB[t];
        po[t] = a.x * a.x + a.y * a.y;
    }
}

// ---------- GEMM: g_part[kc] = P[64-row tile] x W  (LDS-tiled, K split x4) ----------
// grid (64, 4), 256 threads. Thread (rg,cg) owns rows rg*4..+3, cols cg*4..+3.
__global__ __launch_bounds__(256)
void k_gemm2(const float* __restrict__ W) {
    __shared__ float P_lds[64][68];   // [row][kk], pad 68 for write-bank spread
    __shared__ float W_lds[64][68];   // [kk][col]

    const int bm = blockIdx.x;        // row tile
    const int kc = blockIdx.y;        // k chunk
    const int r0 = bm * 64;
    const int ks = kc * 501;
    const int ke = (ks + 501 < NST5) ? ks + 501 : NST5;

    const int tid = threadIdx.x;
    const int rg = tid >> 4;          // 0..15
    const int cg = tid & 15;          // 0..15
    const int srow = tid >> 4;        // staging row-in-pass
    const int sc4 = (tid & 15) * 4;   // staging col

    float acc[4][4];
    #pragma unroll
    for (int i = 0; i < 4; i++)
        #pragma unroll
        for (int j = 0; j < 4; j++) acc[i][j] = 0.f;

    for (int k0 = ks; k0 < ke; k0 += 64) {
        const int kw = ke - k0;       // <=64 valid ks this step
        __syncthreads();
        // stage P: 4 passes of 16 rows; row-major [row][kk]
        #pragma unroll
        for (int p = 0; p < 4; p++) {
            int row = p * 16 + srow;
            float4 v = make_float4(0.f, 0.f, 0.f, 0.f);
            if (sc4 < kw) {
                const float* src = &g_probs[(size_t)(r0 + row) * NST5 + k0 + sc4];
                if (sc4 + 4 <= kw) {
                    v = *(const float4*)src;
                } else {
                    float tmp[4] = {0.f, 0.f, 0.f, 0.f};
                    for (int i = 0; i < kw - sc4; i++) tmp[i] = src[i];
                    v = *(const float4*)tmp;
                }
            }
            *(float4*)&P_lds[row][sc4] = v;
        }
        // stage W: 4 passes of 16 k-rows; [kk][col]
        #pragma unroll
        for (int p = 0; p < 4; p++) {
            int krow = p * 16 + srow;
            float4 v = make_float4(0.f, 0.f, 0.f, 0.f);
            if (krow < kw)
                v = *(const float4*)&W[(size_t)(k0 + krow) * 64 + sc4];
            *(float4*)&W_lds[krow][sc4] = v;
        }
        __syncthreads();

        #pragma unroll 4
        for (int kk = 0; kk < 64; kk++) {
            float4 wv = *(const float4*)&W_lds[kk][cg * 4];
            float pr[4];
            #pragma unroll
            for (int i = 0; i < 4; i++) pr[i] = P_lds[rg * 4 + i][kk];
            #pragma unroll
            for (int i = 0; i < 4; i++) {
                acc[i][0] = fmaf(pr[i], wv.x, acc[i][0]);
                acc[i][1] = fmaf(pr[i], wv.y, acc[i][1]);
                acc[i][2] = fmaf(pr[i], wv.z, acc[i][2]);
                acc[i][3] = fmaf(pr[i], wv.w, acc[i][3]);
            }
        }
    }

    float* po = g_part + ((size_t)kc * BATCH + r0) * 64;
    #pragma unroll
    for (int i = 0; i < 4; i++) {
        float4 v = make_float4(acc[i][0], acc[i][1], acc[i][2], acc[i][3]);
        *(float4*)&po[(size_t)(rg * 4 + i) * 64 + cg * 4] = v;
    }
}

// ---------- reduce 4 partials + bias ----------
__global__ __launch_bounds__(256)
void k_reduce(const float* __restrict__ bias, float* __restrict__ out) {
    int i = blockIdx.x * 256 + threadIdx.x;
    const int TOT = BATCH * 64;
    if (i < TOT) {
        float v = g_part[i] + g_part[TOT + i] + g_part[2 * TOT + i]
                + g_part[3 * TOT + i] + bias[i & 63];
        out[i] = v;
    }
}

extern "C" void kernel_launch(void* const* d_in, const int* in_sizes, int n_in,
                              void* d_out, int out_size, void* d_ws, size_t ws_size,
                              hipStream_t stream) {
    const float* x     = (const float*)d_in[0];
    const float* theta = (const float*)d_in[1];
    const float* W     = (const float*)d_in[2];
    const float* bias  = (const float*)d_in[3];
    float* out = (float*)d_out;
    (void)d_ws; (void)ws_size; (void)in_sizes; (void)n_in; (void)out_size;

    k_tables<<<12, 256, 0, stream>>>();
    k_slos<<<4096, 256, 0, stream>>>(x, theta);
    k_gemm2<<<dim3(64, 4), 256, 0, stream>>>(W);
    k_reduce<<<1024, 256, 0, stream>>>(bias, out);
}

// Round 14
// 112.033 us; speedup vs baseline: 3.1960x; 1.1655x over previous
//
#include <hip/hip_runtime.h>

#define MODES 10
#define NPH 5
#define DEPTH 10
#define NST5 2002
#define BATCH 4096
#define KSPLIT 16
#define KCHUNK 126

// Module-scope scratch: allocated at .so load, fully rewritten every call.
// Packed transitions, per level k (k=0..4), layout [slot][t], slots = k+1:
//   entry = parent_idx | (j << 12) | (occ << 16);  occ==0 => padding (adds 0)
__device__ unsigned g_tbl32[13650];
__device__ float g_probs[(size_t)BATCH * NST5];
__device__ float g_part[(size_t)KSPLIT * BATCH * 64];

// ---------- combinatorics ----------
// count(m, n) = C(n+m-1, m-1), m in [1,10], n in [0,5] -> exact constant LUT
// (i64 mul/div loop here previously made k_tables 134 us: soft i64 divide).
__device__ __forceinline__ int d_count(int m, int n) {
    static const unsigned short C[11][6] = {
        {0, 0, 0, 0, 0, 0},
        {1, 1, 1, 1, 1, 1},
        {1, 2, 3, 4, 5, 6},
        {1, 3, 6, 10, 15, 21},
        {1, 4, 10, 20, 35, 56},
        {1, 5, 15, 35, 70, 126},
        {1, 6, 21, 56, 126, 252},
        {1, 7, 28, 84, 210, 462},
        {1, 8, 36, 120, 330, 792},
        {1, 9, 45, 165, 495, 1287},
        {1, 10, 55, 220, 715, 2002},
    };
    return C[m][n];
}

__device__ void d_unrank(int r, int n, int* s) {
    for (int p = 0; p < MODES; p++) {
        int mm = MODES - p;
        if (mm == 1) { s[p] = n; return; }
        int k = n;
        for (; k >= 0; k--) {
            int c = d_count(mm - 1, n - k);
            if (r < c) break;
            r -= c;
        }
        s[p] = k; n -= k;
    }
}

__device__ int d_rank(const int* s, int n) {
    int r = 0;
    for (int p = 0; p < MODES && n > 0; p++) {
        int mm = MODES - p;
        if (mm == 1) break;
        for (int k = n; k > s[p]; k--) r += d_count(mm - 1, n - k);
        n -= s[p];
    }
    return r;
}

__global__ void k_tables() {
    int id = blockIdx.x * 256 + threadIdx.x;
    if (id >= 3002) return;
    const int sizes[5]  = {10, 55, 220, 715, 2002};
    const int base32[5] = {0, 10, 120, 780, 3640};
    int k = 0, t = id;
    while (k < 5 && t >= sizes[k]) { t -= sizes[k]; k++; }
    int s[10];
    d_unrank(t, k + 1, s);
    int N = sizes[k];
    unsigned* tk = g_tbl32 + base32[k];
    int slot = 0;
    for (int j = 0; j < MODES; j++) {
        if (s[j] > 0) {
            s[j]--;
            int p = d_rank(s, k);
            s[j]++;
            tk[slot * N + t] = (unsigned)p | ((unsigned)j << 12) | ((unsigned)s[j] << 16);
            slot++;
        }
    }
    for (; slot < k + 1; slot++) tk[slot * N + t] = 0u;
}

// ---------- SLOS level step: S = k+1 slots per target state ----------
template<int S>
__device__ __forceinline__ void slos_level(const float2* __restrict__ src,
                                           float2* __restrict__ dst,
                                           const unsigned* __restrict__ tk,
                                           int N, int tid,
                                           const float2 (*Ush)[NPH], int k) {
    for (int t = tid; t < N; t += 256) {
        float ax = 0.f, ay = 0.f;
        #pragma unroll
        for (int sl = 0; sl < S; sl++) {
            unsigned e = tk[sl * N + t];
            int idx = e & 0xFFF;
            int j = (e >> 12) & 0xF;
            float sq = sqrtf((float)(e >> 16));
            float2 a = src[idx];
            float2 u = Ush[j][k];
            float tx = u.x * a.x - u.y * a.y;
            float ty = u.x * a.y + u.y * a.x;
            ax = fmaf(sq, tx, ax);
            ay = fmaf(sq, ty, ay);
        }
        dst[t] = make_float2(ax, ay);
    }
    __syncthreads();
}

// ---------- fused unitary build + SLOS per batch element ----------
__global__ __launch_bounds__(256)
void k_slos(const float* __restrict__ x, const float* __restrict__ theta) {
    __shared__ float2 Ush[MODES][NPH];
    __shared__ float2 ampA[715];   // levels 1 (55), 3 (715)... A holds odd dst
    __shared__ float2 ampB[220];   // level 2 dst

    const int b = blockIdx.x;
    const int tid = threadIdx.x;

    const int r = tid / 5, c = tid % 5;
    const bool act = (tid < 50);
    float2 val = make_float2(0.f, 0.f);
    if (act && r == c) {
        float ang = 6.28318530717958647692f * x[b * MODES + r];
        float s_, c_; sincosf(ang, &s_, &c_);
        val = make_float2(c_, s_);
    }
    for (int l = 0; l < DEPTH; l++) {
        if (act && l > 0) {
            float ang = theta[(l - 1) * MODES + r];
            float s_, c_; sincosf(ang, &s_, &c_);
            float nx = val.x * c_ - val.y * s_;
            float ny = val.x * s_ + val.y * c_;
            val = make_float2(nx, ny);
        }
        if (act) Ush[r][c] = val;
        __syncthreads();
        float2 nv = val;
        if (act) {
            int o = l & 1;
            int lo = r - o;
            int partner = o + (lo ^ 1);
            if (lo >= 0 && partner < MODES) {
                float2 pb = Ush[partner][c];
                const float inv = 0.70710678118654752f;
                nv.x = inv * (val.x - pb.y);
                nv.y = inv * (val.y + pb.x);
            }
        }
        __syncthreads();
        val = nv;
    }
    if (act) Ush[r][c] = val;
    if (tid == 0) ampA[0] = make_float2(1.f, 0.f);
    __syncthreads();

    // levels: k=0 A(1)->B(10); k=1 B->A(55); k=2 A->B(220); k=3 B->A(715);
    // k=4 A(715) -> |.|^2 directly to global (fused, no LDS round-trip).
    // Reuse ampB front as the 10-element buffer for level 0.
    slos_level<1>(ampA, ampB, g_tbl32 + 0,   10,  tid, Ush, 0);
    slos_level<2>(ampB, ampA, g_tbl32 + 10,  55,  tid, Ush, 1);
    slos_level<3>(ampA, ampB, g_tbl32 + 120, 220, tid, Ush, 2);
    slos_level<4>(ampB, ampA, g_tbl32 + 780, 715, tid, Ush, 3);

    float* po = g_probs + (size_t)b * NST5;
    const unsigned* tk = g_tbl32 + 3640;
    for (int t = tid; t < NST5; t += 256) {
        float ax = 0.f, ay = 0.f;
        #pragma unroll
        for (int sl = 0; sl < 5; sl++) {
            unsigned e = tk[sl * NST5 + t];
            int idx = e & 0xFFF;
            int j = (e >> 12) & 0xF;
            float sq = sqrtf((float)(e >> 16));
            float2 a = ampA[idx];
            float2 u = Ush[j][4];
            float tx = u.x * a.x - u.y * a.y;
            float ty = u.x * a.y + u.y * a.x;
            ax = fmaf(sq, tx, ax);
            ay = fmaf(sq, ty, ay);
        }
        po[t] = ax * ax + ay * ay;
    }
}

// ---------- GEMM: g_part[kc] = P[64-row tile] x W  (LDS-tiled, K split x16) ----------
__global__ __launch_bounds__(256)
void k_gemm2(const float* __restrict__ W) {
    __shared__ float P_lds[64][68];
    __shared__ float W_lds[64][68];

    const int bm = blockIdx.x;
    const int kc = blockIdx.y;
    const int r0 = bm * 64;
    const int ks = kc * KCHUNK;
    const int ke = (ks + KCHUNK < NST5) ? ks + KCHUNK : NST5;

    const int tid = threadIdx.x;
    const int rg = tid >> 4;
    const int cg = tid & 15;
    const int srow = tid >> 4;
    const int sc4 = (tid & 15) * 4;

    float acc[4][4];
    #pragma unroll
    for (int i = 0; i < 4; i++)
        #pragma unroll
        for (int j = 0; j < 4; j++) acc[i][j] = 0.f;

    for (int k0 = ks; k0 < ke; k0 += 64) {
        const int kw = ke - k0;
        __syncthreads();
        #pragma unroll
        for (int p = 0; p < 4; p++) {
            int row = p * 16 + srow;
            float4 v = make_float4(0.f, 0.f, 0.f, 0.f);
            if (sc4 < kw) {
                const float* src = &g_probs[(size_t)(r0 + row) * NST5 + k0 + sc4];
                if (sc4 + 4 <= kw) {
                    v = *(const float4*)src;
                } else {
                    float tmp[4] = {0.f, 0.f, 0.f, 0.f};
                    for (int i = 0; i < kw - sc4; i++) tmp[i] = src[i];
                    v = *(const float4*)tmp;
                }
            }
            *(float4*)&P_lds[row][sc4] = v;
        }
        #pragma unroll
        for (int p = 0; p < 4; p++) {
            int krow = p * 16 + srow;
            float4 v = make_float4(0.f, 0.f, 0.f, 0.f);
            if (krow < kw)
                v = *(const float4*)&W[(size_t)(k0 + krow) * 64 + sc4];
            *(float4*)&W_lds[krow][sc4] = v;
        }
        __syncthreads();

        #pragma unroll 4
        for (int kk = 0; kk < 64; kk++) {
            float4 wv = *(const float4*)&W_lds[kk][cg * 4];
            float pr[4];
            #pragma unroll
            for (int i = 0; i < 4; i++) pr[i] = P_lds[rg * 4 + i][kk];
            #pragma unroll
            for (int i = 0; i < 4; i++) {
                acc[i][0] = fmaf(pr[i], wv.x, acc[i][0]);
                acc[i][1] = fmaf(pr[i], wv.y, acc[i][1]);
                acc[i][2] = fmaf(pr[i], wv.z, acc[i][2]);
                acc[i][3] = fmaf(pr[i], wv.w, acc[i][3]);
            }
        }
    }

    float* po = g_part + ((size_t)kc * BATCH + r0) * 64;
    #pragma unroll
    for (int i = 0; i < 4; i++) {
        float4 v = make_float4(acc[i][0], acc[i][1], acc[i][2], acc[i][3]);
        *(float4*)&po[(size_t)(rg * 4 + i) * 64 + cg * 4] = v;
    }
}

// ---------- reduce KSPLIT partials + bias ----------
__global__ __launch_bounds__(256)
void k_reduce(const float* __restrict__ bias, float* __restrict__ out) {
    int i = blockIdx.x * 256 + threadIdx.x;
    const int TOT = BATCH * 64;
    if (i < TOT) {
        float v = bias[i & 63];
        #pragma unroll
        for (int m = 0; m < KSPLIT; m++) v += g_part[(size_t)m * TOT + i];
        out[i] = v;
    }
}

extern "C" void kernel_launch(void* const* d_in, const int* in_sizes, int n_in,
                              void* d_out, int out_size, void* d_ws, size_t ws_size,
                              hipStream_t stream) {
    const float* x     = (const float*)d_in[0];
    const float* theta = (const float*)d_in[1];
    const float* W     = (const float*)d_in[2];
    const float* bias  = (const float*)d_in[3];
    float* out = (float*)d_out;
    (void)d_ws; (void)ws_size; (void)in_sizes; (void)n_in; (void)out_size;

    k_tables<<<12, 256, 0, stream>>>();
    k_slos<<<4096, 256, 0, stream>>>(x, theta);
    k_gemm2<<<dim3(64, KSPLIT), 256, 0, stream>>>(W);
    k_reduce<<<1024, 256, 0, stream>>>(bias, out);
}

// Round 15
// 84.272 us; speedup vs baseline: 4.2488x; 1.3294x over previous
//
#include <hip/hip_runtime.h>

#define MODES 10
#define NPH 5
#define DEPTH 10
#define NST5 2002
#define BATCH 4096
#define KSPLIT 16
#define KCHUNK 126

// Module-scope scratch: allocated at .so load, fully rewritten every call.
// Transition table, per level k (k=0..4), layout [t][slot] with k+1 slots:
//   lo32 = parent_idx | (j << 12);  hi32 = f32 bits of sqrt(occ)
//   padding entries are all-zero (sq = 0.0f adds nothing).
__device__ unsigned long long g_tbl64[13650];
__device__ float2 g_M[MODES][NPH];       // batch-independent mesh matrix cols 0..4
__device__ float g_probs[(size_t)BATCH * NST5];
__device__ float g_part[(size_t)KSPLIT * BATCH * 64];

// ---------- combinatorics ----------
// count(m, n) = C(n+m-1, m-1), m in [1,10], n in [0,5] -> exact constant LUT
// (i64 mul/div loop here previously made k_tables 134 us: soft i64 divide).
__device__ __forceinline__ int d_count(int m, int n) {
    static const unsigned short C[11][6] = {
        {0, 0, 0, 0, 0, 0},
        {1, 1, 1, 1, 1, 1},
        {1, 2, 3, 4, 5, 6},
        {1, 3, 6, 10, 15, 21},
        {1, 4, 10, 20, 35, 56},
        {1, 5, 15, 35, 70, 126},
        {1, 6, 21, 56, 126, 252},
        {1, 7, 28, 84, 210, 462},
        {1, 8, 36, 120, 330, 792},
        {1, 9, 45, 165, 495, 1287},
        {1, 10, 55, 220, 715, 2002},
    };
    return C[m][n];
}

__device__ void d_unrank(int r, int n, int* s) {
    for (int p = 0; p < MODES; p++) {
        int mm = MODES - p;
        if (mm == 1) { s[p] = n; return; }
        int k = n;
        for (; k >= 0; k--) {
            int c = d_count(mm - 1, n - k);
            if (r < c) break;
            r -= c;
        }
        s[p] = k; n -= k;
    }
}

__device__ int d_rank(const int* s, int n) {
    int r = 0;
    for (int p = 0; p < MODES && n > 0; p++) {
        int mm = MODES - p;
        if (mm == 1) break;
        for (int k = n; k > s[p]; k--) r += d_count(mm - 1, n - k);
        n -= s[p];
    }
    return r;
}

__global__ void k_tables() {
    int id = blockIdx.x * 256 + threadIdx.x;
    if (id >= 3002) return;
    const int sizes[5]  = {10, 55, 220, 715, 2002};
    const int base64[5] = {0, 10, 120, 780, 3640};
    int k = 0, t = id;
    while (k < 5 && t >= sizes[k]) { t -= sizes[k]; k++; }
    int s[10];
    d_unrank(t, k + 1, s);
    unsigned long long* tt = g_tbl64 + base64[k] + (size_t)t * (k + 1);
    int slot = 0;
    for (int j = 0; j < MODES; j++) {
        if (s[j] > 0) {
            s[j]--;
            int p = d_rank(s, k);
            s[j]++;
            unsigned meta = (unsigned)p | ((unsigned)j << 12);
            unsigned sqb = __float_as_uint(sqrtf((float)s[j]));
            tt[slot] = (unsigned long long)meta | ((unsigned long long)sqb << 32);
            slot++;
        }
    }
    for (; slot < k + 1; slot++) tt[slot] = 0ull;
}

// ---------- batch-independent mesh matrix M = BS9 D9 ... BS1 D1 BS0 ----------
// (U_b = M . diag(e^{i 2 pi x_b}); SLOS only uses columns 0..4.)
__global__ void k_prep(const float* __restrict__ theta) {
    __shared__ float2 Ush[MODES][NPH];
    const int tid = threadIdx.x;
    const int r = tid / 5, c = tid % 5;
    const bool act = (tid < 50);
    float2 val = make_float2((act && r == c) ? 1.f : 0.f, 0.f);
    for (int l = 0; l < DEPTH; l++) {
        if (act && l > 0) {
            float ang = theta[(l - 1) * MODES + r];
            float s_, c_; sincosf(ang, &s_, &c_);
            float nx = val.x * c_ - val.y * s_;
            float ny = val.x * s_ + val.y * c_;
            val = make_float2(nx, ny);
        }
        if (act) Ush[r][c] = val;
        __syncthreads();
        float2 nv = val;
        if (act) {
            int o = l & 1;
            int lo = r - o;
            int partner = o + (lo ^ 1);
            if (lo >= 0 && partner < MODES) {
                float2 pb = Ush[partner][c];
                const float inv = 0.70710678118654752f;
                nv.x = inv * (val.x - pb.y);
                nv.y = inv * (val.y + pb.x);
            }
        }
        __syncthreads();
        val = nv;
    }
    if (act) g_M[r][c] = val;
}

// ---------- SLOS level: S = k+1 slots per target, 2 batch elems packed ----------
template<int S>
__device__ __forceinline__ void slos_level(const float4* __restrict__ src,
                                           float4* __restrict__ dst,
                                           const unsigned long long* __restrict__ tk,
                                           int N, int tid,
                                           const float4 (*Ush2)[NPH], int k) {
    for (int t = tid; t < N; t += 256) {
        float ax0 = 0.f, ay0 = 0.f, ax1 = 0.f, ay1 = 0.f;
        const unsigned long long* tt = tk + (size_t)t * S;
        #pragma unroll
        for (int sl = 0; sl < S; sl++) {
            unsigned long long e = tt[sl];
            unsigned lo = (unsigned)e;
            float sq = __uint_as_float((unsigned)(e >> 32));
            int idx = lo & 0xFFF;
            int j = (lo >> 12) & 0xF;
            float4 a = src[idx];
            float4 u = Ush2[j][k];
            float tx0 = u.x * a.x - u.y * a.y;
            float ty0 = u.x * a.y + u.y * a.x;
            ax0 = fmaf(sq, tx0, ax0);
            ay0 = fmaf(sq, ty0, ay0);
            float tx1 = u.z * a.z - u.w * a.w;
            float ty1 = u.z * a.w + u.w * a.z;
            ax1 = fmaf(sq, tx1, ax1);
            ay1 = fmaf(sq, ty1, ay1);
        }
        dst[t] = make_float4(ax0, ay0, ax1, ay1);
    }
    __syncthreads();
}

// ---------- SLOS, 2 batch elements per block ----------
__global__ __launch_bounds__(256)
void k_slos(const float* __restrict__ x) {
    __shared__ float4 Ush2[MODES][NPH];  // (b0.re, b0.im, b1.re, b1.im)
    __shared__ float4 ampA2[715];
    __shared__ float4 ampB2[220];

    const int b0 = blockIdx.x * 2;
    const int tid = threadIdx.x;
    const int r = tid / 5, c = tid % 5;

    if (tid < 50) {
        float a0 = 6.28318530717958647692f * x[b0 * MODES + c];
        float a1 = 6.28318530717958647692f * x[(b0 + 1) * MODES + c];
        float s0, c0, s1, c1;
        sincosf(a0, &s0, &c0);
        sincosf(a1, &s1, &c1);
        float2 m = g_M[r][c];
        Ush2[r][c] = make_float4(m.x * c0 - m.y * s0, m.x * s0 + m.y * c0,
                                 m.x * c1 - m.y * s1, m.x * s1 + m.y * c1);
    }
    if (tid == 0) ampA2[0] = make_float4(1.f, 0.f, 1.f, 0.f);
    __syncthreads();

    slos_level<1>(ampA2, ampB2, g_tbl64 + 0,   10,  tid, Ush2, 0);
    slos_level<2>(ampB2, ampA2, g_tbl64 + 10,  55,  tid, Ush2, 1);
    slos_level<3>(ampA2, ampB2, g_tbl64 + 120, 220, tid, Ush2, 2);
    slos_level<4>(ampB2, ampA2, g_tbl64 + 780, 715, tid, Ush2, 3);

    // level 4 fused with |.|^2 -> global (no LDS round-trip)
    float* po0 = g_probs + (size_t)b0 * NST5;
    float* po1 = po0 + NST5;
    const unsigned long long* tk = g_tbl64 + 3640;
    for (int t = tid; t < NST5; t += 256) {
        float ax0 = 0.f, ay0 = 0.f, ax1 = 0.f, ay1 = 0.f;
        const unsigned long long* tt = tk + (size_t)t * 5;
        #pragma unroll
        for (int sl = 0; sl < 5; sl++) {
            unsigned long long e = tt[sl];
            unsigned lo = (unsigned)e;
            float sq = __uint_as_float((unsigned)(e >> 32));
            int idx = lo & 0xFFF;
            int j = (lo >> 12) & 0xF;
            float4 a = ampA2[idx];
            float4 u = Ush2[j][4];
            float tx0 = u.x * a.x - u.y * a.y;
            float ty0 = u.x * a.y + u.y * a.x;
            ax0 = fmaf(sq, tx0, ax0);
            ay0 = fmaf(sq, ty0, ay0);
            float tx1 = u.z * a.z - u.w * a.w;
            float ty1 = u.z * a.w + u.w * a.z;
            ax1 = fmaf(sq, tx1, ax1);
            ay1 = fmaf(sq, ty1, ay1);
        }
        po0[t] = ax0 * ax0 + ay0 * ay0;
        po1[t] = ax1 * ax1 + ay1 * ay1;
    }
}

// ---------- GEMM: g_part[kc] = P[64-row tile] x W  (LDS-tiled, K split x16) ----------
__global__ __launch_bounds__(256)
void k_gemm2(const float* __restrict__ W) {
    __shared__ float P_lds[64][68];
    __shared__ float W_lds[64][68];

    const int bm = blockIdx.x;
    const int kc = blockIdx.y;
    const int r0 = bm * 64;
    const int ks = kc * KCHUNK;
    const int ke = (ks + KCHUNK < NST5) ? ks + KCHUNK : NST5;

    const int tid = threadIdx.x;
    const int rg = tid >> 4;
    const int cg = tid & 15;
    const int srow = tid >> 4;
    const int sc4 = (tid & 15) * 4;

    float acc[4][4];
    #pragma unroll
    for (int i = 0; i < 4; i++)
        #pragma unroll
        for (int j = 0; j < 4; j++) acc[i][j] = 0.f;

    for (int k0 = ks; k0 < ke; k0 += 64) {
        const int kw = ke - k0;
        __syncthreads();
        #pragma unroll
        for (int p = 0; p < 4; p++) {
            int row = p * 16 + srow;
            float4 v = make_float4(0.f, 0.f, 0.f, 0.f);
            if (sc4 < kw) {
                const float* src = &g_probs[(size_t)(r0 + row) * NST5 + k0 + sc4];
                if (sc4 + 4 <= kw) {
                    v = *(const float4*)src;
                } else {
                    float tmp[4] = {0.f, 0.f, 0.f, 0.f};
                    for (int i = 0; i < kw - sc4; i++) tmp[i] = src[i];
                    v = *(const float4*)tmp;
                }
            }
            *(float4*)&P_lds[row][sc4] = v;
        }
        #pragma unroll
        for (int p = 0; p < 4; p++) {
            int krow = p * 16 + srow;
            float4 v = make_float4(0.f, 0.f, 0.f, 0.f);
            if (krow < kw)
                v = *(const float4*)&W[(size_t)(k0 + krow) * 64 + sc4];
            *(float4*)&W_lds[krow][sc4] = v;
        }
        __syncthreads();

        #pragma unroll 4
        for (int kk = 0; kk < 64; kk++) {
            float4 wv = *(const float4*)&W_lds[kk][cg * 4];
            float pr[4];
            #pragma unroll
            for (int i = 0; i < 4; i++) pr[i] = P_lds[rg * 4 + i][kk];
            #pragma unroll
            for (int i = 0; i < 4; i++) {
                acc[i][0] = fmaf(pr[i], wv.x, acc[i][0]);
                acc[i][1] = fmaf(pr[i], wv.y, acc[i][1]);
                acc[i][2] = fmaf(pr[i], wv.z, acc[i][2]);
                acc[i][3] = fmaf(pr[i], wv.w, acc[i][3]);
            }
        }
    }

    float* po = g_part + ((size_t)kc * BATCH + r0) * 64;
    #pragma unroll
    for (int i = 0; i < 4; i++) {
        float4 v = make_float4(acc[i][0], acc[i][1], acc[i][2], acc[i][3]);
        *(float4*)&po[(size_t)(rg * 4 + i) * 64 + cg * 4] = v;
    }
}

// ---------- reduce KSPLIT partials + bias ----------
__global__ __launch_bounds__(256)
void k_reduce(const float* __restrict__ bias, float* __restrict__ out) {
    int i = blockIdx.x * 256 + threadIdx.x;
    const int TOT = BATCH * 64;
    if (i < TOT) {
        float v = bias[i & 63];
        #pragma unroll
        for (int m = 0; m < KSPLIT; m++) v += g_part[(size_t)m * TOT + i];
        out[i] = v;
    }
}

extern "C" void kernel_launch(void* const* d_in, const int* in_sizes, int n_in,
                              void* d_out, int out_size, void* d_ws, size_t ws_size,
                              hipStream_t stream) {
    const float* x     = (const float*)d_in[0];
    const float* theta = (const float*)d_in[1];
    const float* W     = (const float*)d_in[2];
    const float* bias  = (const float*)d_in[3];
    float* out = (float*)d_out;
    (void)d_ws; (void)ws_size; (void)in_sizes; (void)n_in; (void)out_size;

    k_tables<<<12, 256, 0, stream>>>();
    k_prep<<<1, 64, 0, stream>>>(theta);
    k_slos<<<BATCH / 2, 256, 0, stream>>>(x);
    k_gemm2<<<dim3(64, KSPLIT), 256, 0, stream>>>(W);
    k_reduce<<<1024, 256, 0, stream>>>(bias, out);
}